// Round 4
// baseline (345.983 us; speedup 1.0000x reference)
//
#include <hip/hip_runtime.h>

// MHA: B=4 S=2048 D=1024 H=16 DH=64. Full bf16-MFMA pipeline (fp32 accum).
// Threshold is 2% of max|ref| (bf16-tolerant) -> bf16 compute is safe.

#define Bn  4
#define Sn  2048
#define Dn  1024
#define Hn  16
#define DHn 64
#define Mn  (Bn*Sn)          // 8192 rows
#define LDKV 72              // attn V LDS row stride (ushorts)

typedef unsigned short u16;
typedef __attribute__((ext_vector_type(8))) short short8;   // 8 x bf16 (4 VGPRs)
typedef __attribute__((ext_vector_type(4))) short short4v;  // 4 x bf16 (2 VGPRs)
typedef __attribute__((ext_vector_type(4))) float f32x4;    // MFMA C/D frag
typedef __attribute__((ext_vector_type(2))) unsigned int uint2v;

__device__ __forceinline__ u16 f2bf(float f) {
  unsigned u = __float_as_uint(f);
  return (u16)((u + 0x7FFFu + ((u >> 16) & 1u)) >> 16);   // RNE
}

// async 16B/lane global->LDS DMA; lds dest = wave-uniform base + lane*16
__device__ __forceinline__ void async16(const void* g, void* l) {
  __builtin_amdgcn_global_load_lds(
      (const __attribute__((address_space(1))) void*)g,
      (__attribute__((address_space(3))) void*)l, 16, 0, 0);
}

// pack 2 fp32 -> 2 bf16 (truncation) in one v_perm_b32
__device__ __forceinline__ unsigned pk2(float a, float b) {
  return __builtin_amdgcn_perm(__float_as_uint(b), __float_as_uint(a), 0x07060302u);
}

// ---------------- convert: x (f32) -> xb (bf16) ----------------
__global__ __launch_bounds__(256) void k_convert_x(
    const float4* __restrict__ x, ushort4* __restrict__ xb, int n4) {
  int i = blockIdx.x * 256 + threadIdx.x;
  if (i < n4) {
    float4 f = x[i];
    ushort4 o;
    o.x = f2bf(f.x); o.y = f2bf(f.y); o.z = f2bf(f.z); o.w = f2bf(f.w);
    xb[i] = o;
  }
}

// ---- convert+transpose weights to [N][K] bf16 (K contiguous) ----
__global__ __launch_bounds__(256) void k_convert_w(
    const float* __restrict__ Wq, const float* __restrict__ Wk,
    const float* __restrict__ Wv, const float* __restrict__ Wo,
    u16* __restrict__ WqT, u16* __restrict__ WkT,
    u16* __restrict__ WvT, u16* __restrict__ WoT) {
  int i = blockIdx.x * 256 + threadIdx.x;     // 0 .. 4*2^20-1
  int w = i >> 20;
  int o = i & ((1 << 20) - 1);
  int n = o >> 10, d = o & 1023;
  if (w == 3) {
    WoT[o] = f2bf(Wo[d * Dn + n]);
  } else {
    int h = n >> 6, e = n & 63;
    const float* W = (w == 0) ? Wq : (w == 1) ? Wk : Wv;
    u16*         T = (w == 0) ? WqT : (w == 1) ? WkT : WvT;
    T[o] = f2bf(W[h * (Dn * DHn) + d * DHn + e]);
  }
}

// ---------------- QKV projection GEMM (global_load_lds + XOR-8 swizzle) ----------------
// LDS [128][64] unpadded; LDS cell (row, chunk) holds global chunk (chunk ^ (row&7)).
// q: *(0.125*log2e) folding both 1/sqrt(DH) and exp->exp2. v stored [B,H,DH,S].
__global__ __launch_bounds__(256) void k_gemm_qkv(
    const u16* __restrict__ A, const u16* __restrict__ WqT,
    const u16* __restrict__ WkT, const u16* __restrict__ WvT,
    const float* __restrict__ bq, const float* __restrict__ bk,
    const float* __restrict__ bv,
    u16* __restrict__ qO, u16* __restrict__ kO, u16* __restrict__ vO) {
  const int z = blockIdx.z;
  const u16* BT = (z == 0) ? WqT : (z == 1) ? WkT : WvT;
  const float* bias = (z == 0) ? bq : (z == 1) ? bk : bv;
  const int tile_m = blockIdx.x * 128;
  const int tile_n = blockIdx.y * 128;
  const int K = Dn;

  __shared__ u16 As[128 * 64];
  __shared__ u16 Bs[128 * 64];

  const int tid = threadIdx.x;
  const int lane = tid & 63;
  const int wave = tid >> 6;
  const int wm = wave >> 1, wn = wave & 1;
  const int quad = lane >> 4, l16 = lane & 15;
  const int srow8 = lane >> 3;                  // 0..7 row within 8-row group
  const int gchunk = (lane & 7) ^ srow8;        // swizzled global chunk slot
  const int sw = l16 & 7;                       // read-side swizzle

  f32x4 acc[4][4];
#pragma unroll
  for (int i = 0; i < 4; i++)
#pragma unroll
    for (int j = 0; j < 4; j++) acc[i][j] = (f32x4){0.f, 0.f, 0.f, 0.f};

  for (int k0 = 0; k0 < K; k0 += 64) {
#pragma unroll
    for (int q = 0; q < 4; ++q) {               // wave covers rows wave*32..+31
      const int rbase = wave * 32 + q * 8;
      async16(&A[(size_t)(tile_m + rbase + srow8) * K + k0 + gchunk * 8],
              &As[rbase * 64]);
      async16(&BT[(size_t)(tile_n + rbase + srow8) * K + k0 + gchunk * 8],
              &Bs[rbase * 64]);
    }
    __syncthreads();                            // drains vmcnt -> LDS visible
#pragma unroll
    for (int ks = 0; ks < 2; ++ks) {
      short8 a[4], b[4];
#pragma unroll
      for (int i = 0; i < 4; i++)
        a[i] = *(const short8*)&As[(wm * 64 + i * 16 + l16) * 64 + (((ks * 4 + quad) ^ sw)) * 8];
#pragma unroll
      for (int j = 0; j < 4; j++)
        b[j] = *(const short8*)&Bs[(wn * 64 + j * 16 + l16) * 64 + (((ks * 4 + quad) ^ sw)) * 8];
#pragma unroll
      for (int i = 0; i < 4; i++)
#pragma unroll
        for (int j = 0; j < 4; j++)
          acc[i][j] = __builtin_amdgcn_mfma_f32_16x16x32_bf16(a[i], b[j], acc[i][j], 0, 0, 0);
    }
    __syncthreads();                            // protect LDS before next DMA
  }

  // q scale = 0.125 * log2(e): folds 1/sqrt(64) and exp->exp2 conversion
  const float scale = (z == 0) ? 0.18033688011112042f : 1.0f;
#pragma unroll
  for (int i = 0; i < 4; i++) {
    const int mbase = tile_m + wm * 64 + i * 16 + quad * 4;
#pragma unroll
    for (int j = 0; j < 4; j++) {
      const int n = tile_n + wn * 64 + j * 16 + l16;
      const float bn = bias[n];
      const int h = n >> 6, e = n & 63;
#pragma unroll
      for (int r = 0; r < 4; r++) {
        const int m = mbase + r;
        const int bb = m >> 11, s = m & 2047;
        const u16 val = f2bf((acc[i][j][r] + bn) * scale);
        if (z == 2)
          vO[((size_t)(bb * Hn + h) * DHn + e) * Sn + s] = val;     // [B,H,DH,S]
        else if (z == 1)
          kO[((size_t)(bb * Hn + h) * Sn + s) * DHn + e] = val;
        else
          qO[((size_t)(bb * Hn + h) * Sn + s) * DHn + e] = val;
      }
    }
  }
}

// ---------------- flash attention ----------------
// grid (S/128, B*H), 4 waves, wave owns 32 q-rows. Transposed-S: P^T C-frag is
// directly the PV A-operand (verified R2/R3). Per 64-key tile:
//   K staged via global_load_lds + XOR-8 swizzle (no VGPR roundtrip),
//   V staged via VGPR with key-permuted cols: col' = quad*16 + g*4 + r, so PV
//   B-frags come from 8 b128 reads (was 32 b64). exp2 (log2e pre-folded into q),
//   P packed by v_perm truncation. One barrier/tile, double-buffered.
__global__ __launch_bounds__(256) void k_attn(
    const u16* __restrict__ qg, const u16* __restrict__ kg,
    const u16* __restrict__ vg, u16* __restrict__ ctx) {
  const int bh = blockIdx.y;
  const int b = bh >> 4, h = bh & 15;
  const int tid = threadIdx.x;
  const int wave = tid >> 6, lane = tid & 63;
  const int quad = lane >> 4, l16 = lane & 15;
  const int qbase = blockIdx.x * 128 + wave * 32;

  const u16* qp = qg + (size_t)bh * Sn * DHn;
  const u16* kp = kg + (size_t)bh * Sn * DHn;
  const u16* vp = vg + (size_t)bh * DHn * Sn;   // [DH][S]

  __shared__ u16 Ks[2][64 * 64];                // swizzled, unpadded (DMA dest)
  __shared__ u16 Vs[2][64 * LDKV];              // key-permuted cols

  const int srow8 = lane >> 3;
  const int gchunk = (lane & 7) ^ srow8;
  const int sw = l16 & 7;

  const int vrow = tid >> 3;                    // 0..31
  const int vc = tid & 7;
  const int vcl = ((2 * vc) & 3) * 16 + (vc >> 1) * 4;       // keys vc*8+0..3
  const int vch = ((2 * vc + 1) & 3) * 16 + (vc >> 1) * 4;   // keys vc*8+4..7

  // Q as B-operand of 16x16x32: B[n=q=l16][k=d=quad*8+j], two 16-q groups
  short8 bq[2][2];
#pragma unroll
  for (int g2 = 0; g2 < 2; g2++) {
    bq[g2][0] = *(const short8*)&qp[(size_t)(qbase + g2 * 16 + l16) * DHn + quad * 8];
    bq[g2][1] = *(const short8*)&qp[(size_t)(qbase + g2 * 16 + l16) * DHn + 32 + quad * 8];
  }

  f32x4 octx[2][4];
#pragma unroll
  for (int g2 = 0; g2 < 2; g2++)
#pragma unroll
    for (int j = 0; j < 4; j++) octx[g2][j] = (f32x4){0.f, 0.f, 0.f, 0.f};
  float lr[2] = {0.f, 0.f};

  // prologue: stage tile 0
  {
    const int rbase = wave * 16;
    async16(&kp[(size_t)(rbase + srow8) * DHn + gchunk * 8], &Ks[0][rbase * 64]);
    async16(&kp[(size_t)(rbase + 8 + srow8) * DHn + gchunk * 8], &Ks[0][(rbase + 8) * 64]);
    uint4 vv0 = *(const uint4*)&vp[(size_t)vrow * Sn + vc * 8];
    uint4 vv1 = *(const uint4*)&vp[(size_t)(32 + vrow) * Sn + vc * 8];
    *(uint2*)&Vs[0][vrow * LDKV + vcl] = make_uint2(vv0.x, vv0.y);
    *(uint2*)&Vs[0][vrow * LDKV + vch] = make_uint2(vv0.z, vv0.w);
    *(uint2*)&Vs[0][(32 + vrow) * LDKV + vcl] = make_uint2(vv1.x, vv1.y);
    *(uint2*)&Vs[0][(32 + vrow) * LDKV + vch] = make_uint2(vv1.z, vv1.w);
  }
  __syncthreads();

  uint4 vv0, vv1;
  for (int kt = 0; kt < Sn / 64; ++kt) {
    const int cur = kt & 1, nxt = cur ^ 1;
    const bool more = (kt + 1 < Sn / 64);
    if (more) {
      const int key1 = (kt + 1) * 64;
      const int rbase = wave * 16;
      async16(&kp[(size_t)(key1 + rbase + srow8) * DHn + gchunk * 8], &Ks[nxt][rbase * 64]);
      async16(&kp[(size_t)(key1 + rbase + 8 + srow8) * DHn + gchunk * 8], &Ks[nxt][(rbase + 8) * 64]);
      vv0 = *(const uint4*)&vp[(size_t)vrow * Sn + key1 + vc * 8];
      vv1 = *(const uint4*)&vp[(size_t)(32 + vrow) * Sn + key1 + vc * 8];
    }

    // S^T = K·Q^T, p = exp2(s): 4 key-groups of 16
    short4v ap[2][4];
#pragma unroll
    for (int g = 0; g < 4; g++) {
      short8 ka0 = *(const short8*)&Ks[cur][(g * 16 + l16) * 64 + (quad ^ sw) * 8];
      short8 ka1 = *(const short8*)&Ks[cur][(g * 16 + l16) * 64 + ((quad + 4) ^ sw) * 8];
#pragma unroll
      for (int g2 = 0; g2 < 2; g2++) {
        f32x4 sc = (f32x4){0.f, 0.f, 0.f, 0.f};
        sc = __builtin_amdgcn_mfma_f32_16x16x32_bf16(ka0, bq[g2][0], sc, 0, 0, 0);
        sc = __builtin_amdgcn_mfma_f32_16x16x32_bf16(ka1, bq[g2][1], sc, 0, 0, 0);
        float p[4];
#pragma unroll
        for (int r = 0; r < 4; r++) p[r] = exp2f(sc[r]);
        lr[g2] += (p[0] + p[1]) + (p[2] + p[3]);
        ap[g2][g] = __builtin_bit_cast(short4v,
            (uint2v){pk2(p[0], p[1]), pk2(p[2], p[3])});
      }
    }

    // ctx += P·V : B-frags for all 4 key-groups from 2 b128 reads per j
#pragma unroll
    for (int j = 0; j < 4; j++) {
      const int ro = (j * 16 + l16) * LDKV + quad * 16;
      short8 v01 = *(const short8*)&Vs[cur][ro];
      short8 v23 = *(const short8*)&Vs[cur][ro + 8];
      short4v vb[4] = {
          {v01[0], v01[1], v01[2], v01[3]}, {v01[4], v01[5], v01[6], v01[7]},
          {v23[0], v23[1], v23[2], v23[3]}, {v23[4], v23[5], v23[6], v23[7]}};
#pragma unroll
      for (int g = 0; g < 4; g++) {
        octx[0][j] = __builtin_amdgcn_mfma_f32_16x16x16bf16_1k(ap[0][g], vb[g], octx[0][j], 0, 0, 0);
        octx[1][j] = __builtin_amdgcn_mfma_f32_16x16x16bf16_1k(ap[1][g], vb[g], octx[1][j], 0, 0, 0);
      }
    }

    if (more) {
      *(uint2*)&Vs[nxt][vrow * LDKV + vcl] = make_uint2(vv0.x, vv0.y);
      *(uint2*)&Vs[nxt][vrow * LDKV + vch] = make_uint2(vv0.z, vv0.w);
      *(uint2*)&Vs[nxt][(32 + vrow) * LDKV + vcl] = make_uint2(vv1.x, vv1.y);
      *(uint2*)&Vs[nxt][(32 + vrow) * LDKV + vch] = make_uint2(vv1.z, vv1.w);
    }
    __syncthreads();
  }

  // l-reduction: sum over quads, broadcast to D-layout rows (q=quad*4+r)
#pragma unroll
  for (int g2 = 0; g2 < 2; g2++) {
    lr[g2] += __shfl_xor(lr[g2], 16, 64);
    lr[g2] += __shfl_xor(lr[g2], 32, 64);
  }
  float rl[2][4];
#pragma unroll
  for (int g2 = 0; g2 < 2; g2++)
#pragma unroll
    for (int r = 0; r < 4; r++)
      rl[g2][r] = 1.0f / __shfl(lr[g2], quad * 4 + r, 64);

#pragma unroll
  for (int g2 = 0; g2 < 2; g2++)
#pragma unroll
    for (int j = 0; j < 4; j++) {
      const int n = h * DHn + j * 16 + l16;
#pragma unroll
      for (int r = 0; r < 4; r++) {
        const int s = qbase + g2 * 16 + quad * 4 + r;
        ctx[(size_t)(b * Sn + s) * Dn + n] = f2bf(octx[g2][j][r] * rl[g2][r]);
      }
    }
}

// ---------------- output projection GEMM (global_load_lds + XOR-8 swizzle) ----------------
__global__ __launch_bounds__(256) void k_gemm_out(
    const u16* __restrict__ A, const u16* __restrict__ WoT,
    const float* __restrict__ bo, float* __restrict__ out) {
  const int tile_m = blockIdx.x * 128;
  const int tile_n = blockIdx.y * 128;
  const int K = Dn;

  __shared__ u16 As[128 * 64];
  __shared__ u16 Bs[128 * 64];

  const int tid = threadIdx.x;
  const int lane = tid & 63;
  const int wave = tid >> 6;
  const int wm = wave >> 1, wn = wave & 1;
  const int quad = lane >> 4, l16 = lane & 15;
  const int srow8 = lane >> 3;
  const int gchunk = (lane & 7) ^ srow8;
  const int sw = l16 & 7;

  f32x4 acc[4][4];
#pragma unroll
  for (int i = 0; i < 4; i++)
#pragma unroll
    for (int j = 0; j < 4; j++) acc[i][j] = (f32x4){0.f, 0.f, 0.f, 0.f};

  for (int k0 = 0; k0 < K; k0 += 64) {
#pragma unroll
    for (int q = 0; q < 4; ++q) {
      const int rbase = wave * 32 + q * 8;
      async16(&A[(size_t)(tile_m + rbase + srow8) * K + k0 + gchunk * 8],
              &As[rbase * 64]);
      async16(&WoT[(size_t)(tile_n + rbase + srow8) * K + k0 + gchunk * 8],
              &Bs[rbase * 64]);
    }
    __syncthreads();
#pragma unroll
    for (int ks = 0; ks < 2; ++ks) {
      short8 a[4], b[4];
#pragma unroll
      for (int i = 0; i < 4; i++)
        a[i] = *(const short8*)&As[(wm * 64 + i * 16 + l16) * 64 + (((ks * 4 + quad) ^ sw)) * 8];
#pragma unroll
      for (int j = 0; j < 4; j++)
        b[j] = *(const short8*)&Bs[(wn * 64 + j * 16 + l16) * 64 + (((ks * 4 + quad) ^ sw)) * 8];
#pragma unroll
      for (int i = 0; i < 4; i++)
#pragma unroll
        for (int j = 0; j < 4; j++)
          acc[i][j] = __builtin_amdgcn_mfma_f32_16x16x32_bf16(a[i], b[j], acc[i][j], 0, 0, 0);
    }
    __syncthreads();
  }

#pragma unroll
  for (int i = 0; i < 4; i++) {
    const int mbase = tile_m + wm * 64 + i * 16 + quad * 4;
#pragma unroll
    for (int j = 0; j < 4; j++) {
      const int n = tile_n + wn * 64 + j * 16 + l16;
      const float bn = bo[n];
#pragma unroll
      for (int r = 0; r < 4; r++)
        out[(size_t)(mbase + r) * Dn + n] = acc[i][j][r] + bn;
    }
  }
}

extern "C" void kernel_launch(void* const* d_in, const int* in_sizes, int n_in,
                              void* d_out, int out_size, void* d_ws, size_t ws_size,
                              hipStream_t stream) {
  const float* x  = (const float*)d_in[0];
  const float* Wq = (const float*)d_in[1];
  const float* bq = (const float*)d_in[2];
  const float* Wk = (const float*)d_in[3];
  const float* bk = (const float*)d_in[4];
  const float* Wv = (const float*)d_in[5];
  const float* bv = (const float*)d_in[6];
  const float* Wo = (const float*)d_in[7];
  const float* bo = (const float*)d_in[8];
  float* out = (float*)d_out;

  // workspace carve-up (ctx aliases xb: xb dead after k_gemm_qkv) — ~75.5 MB
  char* ws = (char*)d_ws;
  u16* xb  = (u16*)ws;  ws += (size_t)Mn * Dn * 2;
  u16* WqT = (u16*)ws;  ws += (size_t)Dn * Dn * 2;
  u16* WkT = (u16*)ws;  ws += (size_t)Dn * Dn * 2;
  u16* WvT = (u16*)ws;  ws += (size_t)Dn * Dn * 2;
  u16* WoT = (u16*)ws;  ws += (size_t)Dn * Dn * 2;
  u16* qb  = (u16*)ws;  ws += (size_t)Mn * Dn * 2;
  u16* kb  = (u16*)ws;  ws += (size_t)Mn * Dn * 2;
  u16* vtb = (u16*)ws;  ws += (size_t)Mn * Dn * 2;
  u16* ctx = xb;        // alias

  k_convert_x<<<(Mn * Dn / 4) / 256, 256, 0, stream>>>((const float4*)x, (ushort4*)xb, Mn * Dn / 4);
  k_convert_w<<<(4 * Dn * Dn) / 256, 256, 0, stream>>>(Wq, Wk, Wv, Wo, WqT, WkT, WvT, WoT);

  dim3 g1(Mn / 128, Dn / 128, 3);
  k_gemm_qkv<<<g1, 256, 0, stream>>>(xb, WqT, WkT, WvT, bq, bk, bv, qb, kb, vtb);

  dim3 g2(Sn / 128, Bn * Hn);
  k_attn<<<g2, 256, 0, stream>>>(qb, kb, vtb, ctx);

  dim3 g3(Mn / 128, Dn / 128);
  k_gemm_out<<<g3, 256, 0, stream>>>(ctx, WoT, bo, out);
}

// Round 5
// 304.289 us; speedup vs baseline: 1.1370x; 1.1370x over previous
//
#include <hip/hip_runtime.h>

// MHA: B=4 S=2048 D=1024 H=16 DH=64. Full bf16-MFMA pipeline (fp32 accum).

#define Bn  4
#define Sn  2048
#define Dn  1024
#define Hn  16
#define DHn 64
#define Mn  (Bn*Sn)          // 8192 rows
#define LDKV 72              // attn V LDS row stride (ushorts)

typedef unsigned short u16;
typedef __attribute__((ext_vector_type(8))) short short8;   // 8 x bf16 (4 VGPRs)
typedef __attribute__((ext_vector_type(4))) short short4v;  // 4 x bf16 (2 VGPRs)
typedef __attribute__((ext_vector_type(4))) float f32x4;    // MFMA C/D frag
typedef __attribute__((ext_vector_type(2))) unsigned int uint2v;

__device__ __forceinline__ u16 f2bf(float f) {
  unsigned u = __float_as_uint(f);
  return (u16)((u + 0x7FFFu + ((u >> 16) & 1u)) >> 16);   // RNE
}

// async 16B/lane global->LDS DMA; lds dest = wave-uniform base + lane*16
__device__ __forceinline__ void async16(const void* g, void* l) {
  __builtin_amdgcn_global_load_lds(
      (const __attribute__((address_space(1))) void*)g,
      (__attribute__((address_space(3))) void*)l, 16, 0, 0);
}

// pack 2 fp32 -> 2 bf16 (truncation) in one v_perm_b32
__device__ __forceinline__ unsigned pk2(float a, float b) {
  return __builtin_amdgcn_perm(__float_as_uint(b), __float_as_uint(a), 0x07060302u);
}

// ---------------- convert: x (f32) -> xb (bf16) ----------------
__global__ __launch_bounds__(256) void k_convert_x(
    const float4* __restrict__ x, ushort4* __restrict__ xb, int n4) {
  int i = blockIdx.x * 256 + threadIdx.x;
  if (i < n4) {
    float4 f = x[i];
    ushort4 o;
    o.x = f2bf(f.x); o.y = f2bf(f.y); o.z = f2bf(f.z); o.w = f2bf(f.w);
    xb[i] = o;
  }
}

// ---- convert+transpose weights to [N][K] bf16 via LDS 64x64 tiles ----
// Both read and write phases fully coalesced; LDS stride 65 -> conflict-free.
__global__ __launch_bounds__(256) void k_convert_w(
    const float* __restrict__ Wq, const float* __restrict__ Wk,
    const float* __restrict__ Wv, const float* __restrict__ Wo,
    u16* __restrict__ WqT, u16* __restrict__ WkT,
    u16* __restrict__ WvT, u16* __restrict__ WoT) {
  __shared__ float t[64][65];
  const int bid = blockIdx.x;          // 0..1023
  const int wsel = bid >> 8;           // 0..3
  const int idx = bid & 255;
  const int tid = threadIdx.x;
  const int c = tid & 63;
  const int r4 = tid >> 6;             // 0..3

  if (wsel < 3) {
    // W[h][d][e] -> T[n=h*64+e][d]
    const float* W = (wsel == 0) ? Wq : (wsel == 1) ? Wk : Wv;
    u16* T = (wsel == 0) ? WqT : (wsel == 1) ? WkT : WvT;
    const int h = idx >> 4;
    const int d0 = (idx & 15) * 64;
    const float* src = W + (size_t)h * (Dn * DHn) + (size_t)d0 * DHn;
#pragma unroll
    for (int r = 0; r < 16; r++) {
      int row = r * 4 + r4;                       // d'
      t[row][c] = src[row * DHn + c];             // e = c (coalesced)
    }
    __syncthreads();
    u16* dst = T + (size_t)(h * 64) * Dn + d0;
#pragma unroll
    for (int r = 0; r < 16; r++) {
      int erow = r * 4 + r4;
      dst[(size_t)erow * Dn + c] = f2bf(t[c][erow]);   // d = c (coalesced)
    }
  } else {
    // Wo[d][n] -> T[n][d]
    const int n0 = (idx >> 4) * 64;
    const int d0 = (idx & 15) * 64;
#pragma unroll
    for (int r = 0; r < 16; r++) {
      int row = r * 4 + r4;                       // d'
      t[row][c] = Wo[(size_t)(d0 + row) * Dn + n0 + c];
    }
    __syncthreads();
#pragma unroll
    for (int r = 0; r < 16; r++) {
      int nrow = r * 4 + r4;
      WoT[(size_t)(n0 + nrow) * Dn + d0 + c] = f2bf(t[c][nrow]);
    }
  }
}

// ---------------- QKV projection GEMM (global_load_lds + XOR-8 swizzle) ----------------
// q: *(0.125*log2e) folding 1/sqrt(DH) and exp->exp2. v stored [B,H,DH,S].
__global__ __launch_bounds__(256) void k_gemm_qkv(
    const u16* __restrict__ A, const u16* __restrict__ WqT,
    const u16* __restrict__ WkT, const u16* __restrict__ WvT,
    const float* __restrict__ bq, const float* __restrict__ bk,
    const float* __restrict__ bv,
    u16* __restrict__ qO, u16* __restrict__ kO, u16* __restrict__ vO) {
  const int z = blockIdx.z;
  const u16* BT = (z == 0) ? WqT : (z == 1) ? WkT : WvT;
  const float* bias = (z == 0) ? bq : (z == 1) ? bk : bv;
  const int tile_m = blockIdx.x * 128;
  const int tile_n = blockIdx.y * 128;
  const int K = Dn;

  __shared__ u16 As[128 * 64];
  __shared__ u16 Bs[128 * 64];

  const int tid = threadIdx.x;
  const int lane = tid & 63;
  const int wave = tid >> 6;
  const int wm = wave >> 1, wn = wave & 1;
  const int quad = lane >> 4, l16 = lane & 15;
  const int srow8 = lane >> 3;
  const int gchunk = (lane & 7) ^ srow8;
  const int sw = l16 & 7;

  f32x4 acc[4][4];
#pragma unroll
  for (int i = 0; i < 4; i++)
#pragma unroll
    for (int j = 0; j < 4; j++) acc[i][j] = (f32x4){0.f, 0.f, 0.f, 0.f};

  for (int k0 = 0; k0 < K; k0 += 64) {
#pragma unroll
    for (int q = 0; q < 4; ++q) {
      const int rbase = wave * 32 + q * 8;
      async16(&A[(size_t)(tile_m + rbase + srow8) * K + k0 + gchunk * 8],
              &As[rbase * 64]);
      async16(&BT[(size_t)(tile_n + rbase + srow8) * K + k0 + gchunk * 8],
              &Bs[rbase * 64]);
    }
    __syncthreads();
#pragma unroll
    for (int ks = 0; ks < 2; ++ks) {
      short8 a[4], b[4];
#pragma unroll
      for (int i = 0; i < 4; i++)
        a[i] = *(const short8*)&As[(wm * 64 + i * 16 + l16) * 64 + (((ks * 4 + quad) ^ sw)) * 8];
#pragma unroll
      for (int j = 0; j < 4; j++)
        b[j] = *(const short8*)&Bs[(wn * 64 + j * 16 + l16) * 64 + (((ks * 4 + quad) ^ sw)) * 8];
#pragma unroll
      for (int i = 0; i < 4; i++)
#pragma unroll
        for (int j = 0; j < 4; j++)
          acc[i][j] = __builtin_amdgcn_mfma_f32_16x16x32_bf16(a[i], b[j], acc[i][j], 0, 0, 0);
    }
    __syncthreads();
  }

  // q scale = 0.125 * log2(e)
  const float scale = (z == 0) ? 0.18033688011112042f : 1.0f;
#pragma unroll
  for (int i = 0; i < 4; i++) {
    const int mbase = tile_m + wm * 64 + i * 16 + quad * 4;
#pragma unroll
    for (int j = 0; j < 4; j++) {
      const int n = tile_n + wn * 64 + j * 16 + l16;
      const float bn = bias[n];
      const int h = n >> 6, e = n & 63;
#pragma unroll
      for (int r = 0; r < 4; r++) {
        const int m = mbase + r;
        const int bb = m >> 11, s = m & 2047;
        const u16 val = f2bf((acc[i][j][r] + bn) * scale);
        if (z == 2)
          vO[((size_t)(bb * Hn + h) * DHn + e) * Sn + s] = val;     // [B,H,DH,S]
        else if (z == 1)
          kO[((size_t)(bb * Hn + h) * Sn + s) * DHn + e] = val;
        else
          qO[((size_t)(bb * Hn + h) * Sn + s) * DHn + e] = val;
      }
    }
  }
}

// ---------------- flash attention ----------------
// grid (S/128, B*H), 4 waves, wave owns 32 q-rows. Transposed-S: P^T C-frag is
// directly the PV A-operand. K staged via global_load_lds + XOR-8 swizzle;
// V staged plain [DH][64key] stride-72, PV B-frags = direct b64 reads.
// exp2 via raw v_exp_f32 builtin (log2e pre-folded in q); P packed by v_perm.
__global__ __launch_bounds__(256) void k_attn(
    const u16* __restrict__ qg, const u16* __restrict__ kg,
    const u16* __restrict__ vg, u16* __restrict__ ctx) {
  const int bh = blockIdx.y;
  const int b = bh >> 4, h = bh & 15;
  const int tid = threadIdx.x;
  const int wave = tid >> 6, lane = tid & 63;
  const int quad = lane >> 4, l16 = lane & 15;
  const int qbase = blockIdx.x * 128 + wave * 32;

  const u16* qp = qg + (size_t)bh * Sn * DHn;
  const u16* kp = kg + (size_t)bh * Sn * DHn;
  const u16* vp = vg + (size_t)bh * DHn * Sn;   // [DH][S]

  __shared__ u16 Ks[2][64 * 64];                // swizzled, unpadded (DMA dest)
  __shared__ u16 Vs[2][64 * LDKV];              // plain [DH][key], stride 72

  const int srow8 = lane >> 3;
  const int gchunk = (lane & 7) ^ srow8;
  const int sw = l16 & 7;

  const int vrow = tid >> 3;                    // 0..31
  const int vc = tid & 7;

  // Q as B-operand of 16x16x32: B[n=q=l16][k=d=quad*8+j], two 16-q groups
  short8 bq[2][2];
#pragma unroll
  for (int g2 = 0; g2 < 2; g2++) {
    bq[g2][0] = *(const short8*)&qp[(size_t)(qbase + g2 * 16 + l16) * DHn + quad * 8];
    bq[g2][1] = *(const short8*)&qp[(size_t)(qbase + g2 * 16 + l16) * DHn + 32 + quad * 8];
  }

  f32x4 octx[2][4];
#pragma unroll
  for (int g2 = 0; g2 < 2; g2++)
#pragma unroll
    for (int j = 0; j < 4; j++) octx[g2][j] = (f32x4){0.f, 0.f, 0.f, 0.f};
  float lr[2] = {0.f, 0.f};

  // prologue: stage tile 0
  {
    const int rbase = wave * 16;
    async16(&kp[(size_t)(rbase + srow8) * DHn + gchunk * 8], &Ks[0][rbase * 64]);
    async16(&kp[(size_t)(rbase + 8 + srow8) * DHn + gchunk * 8], &Ks[0][(rbase + 8) * 64]);
    uint4 vv0 = *(const uint4*)&vp[(size_t)vrow * Sn + vc * 8];
    uint4 vv1 = *(const uint4*)&vp[(size_t)(32 + vrow) * Sn + vc * 8];
    *(uint4*)&Vs[0][vrow * LDKV + vc * 8] = vv0;
    *(uint4*)&Vs[0][(32 + vrow) * LDKV + vc * 8] = vv1;
  }
  __syncthreads();

  uint4 vv0, vv1;
  for (int kt = 0; kt < Sn / 64; ++kt) {
    const int cur = kt & 1, nxt = cur ^ 1;
    const bool more = (kt + 1 < Sn / 64);
    if (more) {
      const int key1 = (kt + 1) * 64;
      const int rbase = wave * 16;
      async16(&kp[(size_t)(key1 + rbase + srow8) * DHn + gchunk * 8], &Ks[nxt][rbase * 64]);
      async16(&kp[(size_t)(key1 + rbase + 8 + srow8) * DHn + gchunk * 8], &Ks[nxt][(rbase + 8) * 64]);
      vv0 = *(const uint4*)&vp[(size_t)vrow * Sn + key1 + vc * 8];
      vv1 = *(const uint4*)&vp[(size_t)(32 + vrow) * Sn + key1 + vc * 8];
    }

    // S^T = K·Q^T, p = exp2(s): 4 key-groups of 16
    short4v ap[2][4];
#pragma unroll
    for (int g = 0; g < 4; g++) {
      short8 ka0 = *(const short8*)&Ks[cur][(g * 16 + l16) * 64 + (quad ^ sw) * 8];
      short8 ka1 = *(const short8*)&Ks[cur][(g * 16 + l16) * 64 + ((quad + 4) ^ sw) * 8];
#pragma unroll
      for (int g2 = 0; g2 < 2; g2++) {
        f32x4 sc = (f32x4){0.f, 0.f, 0.f, 0.f};
        sc = __builtin_amdgcn_mfma_f32_16x16x32_bf16(ka0, bq[g2][0], sc, 0, 0, 0);
        sc = __builtin_amdgcn_mfma_f32_16x16x32_bf16(ka1, bq[g2][1], sc, 0, 0, 0);
        float p[4];
#pragma unroll
        for (int r = 0; r < 4; r++) p[r] = __builtin_amdgcn_exp2f(sc[r]);
        lr[g2] += (p[0] + p[1]) + (p[2] + p[3]);
        ap[g2][g] = __builtin_bit_cast(short4v,
            (uint2v){pk2(p[0], p[1]), pk2(p[2], p[3])});
      }
    }

    // ctx += P·V : direct b64 B-frag reads from plain V tile
#pragma unroll
    for (int j = 0; j < 4; j++) {
#pragma unroll
      for (int g = 0; g < 4; g++) {
        short4v vb = *(const short4v*)&Vs[cur][(j * 16 + l16) * LDKV + g * 16 + quad * 4];
        octx[0][j] = __builtin_amdgcn_mfma_f32_16x16x16bf16_1k(ap[0][g], vb, octx[0][j], 0, 0, 0);
        octx[1][j] = __builtin_amdgcn_mfma_f32_16x16x16bf16_1k(ap[1][g], vb, octx[1][j], 0, 0, 0);
      }
    }

    if (more) {
      *(uint4*)&Vs[nxt][vrow * LDKV + vc * 8] = vv0;
      *(uint4*)&Vs[nxt][(32 + vrow) * LDKV + vc * 8] = vv1;
    }
    __syncthreads();
  }

  // l-reduction: sum over quads, broadcast to D-layout rows (q=quad*4+r)
#pragma unroll
  for (int g2 = 0; g2 < 2; g2++) {
    lr[g2] += __shfl_xor(lr[g2], 16, 64);
    lr[g2] += __shfl_xor(lr[g2], 32, 64);
  }
  float rl[2][4];
#pragma unroll
  for (int g2 = 0; g2 < 2; g2++)
#pragma unroll
    for (int r = 0; r < 4; r++)
      rl[g2][r] = 1.0f / __shfl(lr[g2], quad * 4 + r, 64);

#pragma unroll
  for (int g2 = 0; g2 < 2; g2++)
#pragma unroll
    for (int j = 0; j < 4; j++) {
      const int n = h * DHn + j * 16 + l16;
#pragma unroll
      for (int r = 0; r < 4; r++) {
        const int s = qbase + g2 * 16 + quad * 4 + r;
        ctx[(size_t)(b * Sn + s) * Dn + n] = f2bf(octx[g2][j][r] * rl[g2][r]);
      }
    }
}

// ---------------- output projection GEMM (global_load_lds + XOR-8 swizzle) ----------------
__global__ __launch_bounds__(256) void k_gemm_out(
    const u16* __restrict__ A, const u16* __restrict__ WoT,
    const float* __restrict__ bo, float* __restrict__ out) {
  const int tile_m = blockIdx.x * 128;
  const int tile_n = blockIdx.y * 128;
  const int K = Dn;

  __shared__ u16 As[128 * 64];
  __shared__ u16 Bs[128 * 64];

  const int tid = threadIdx.x;
  const int lane = tid & 63;
  const int wave = tid >> 6;
  const int wm = wave >> 1, wn = wave & 1;
  const int quad = lane >> 4, l16 = lane & 15;
  const int srow8 = lane >> 3;
  const int gchunk = (lane & 7) ^ srow8;
  const int sw = l16 & 7;

  f32x4 acc[4][4];
#pragma unroll
  for (int i = 0; i < 4; i++)
#pragma unroll
    for (int j = 0; j < 4; j++) acc[i][j] = (f32x4){0.f, 0.f, 0.f, 0.f};

  for (int k0 = 0; k0 < K; k0 += 64) {
#pragma unroll
    for (int q = 0; q < 4; ++q) {
      const int rbase = wave * 32 + q * 8;
      async16(&A[(size_t)(tile_m + rbase + srow8) * K + k0 + gchunk * 8],
              &As[rbase * 64]);
      async16(&WoT[(size_t)(tile_n + rbase + srow8) * K + k0 + gchunk * 8],
              &Bs[rbase * 64]);
    }
    __syncthreads();
#pragma unroll
    for (int ks = 0; ks < 2; ++ks) {
      short8 a[4], b[4];
#pragma unroll
      for (int i = 0; i < 4; i++)
        a[i] = *(const short8*)&As[(wm * 64 + i * 16 + l16) * 64 + (((ks * 4 + quad) ^ sw)) * 8];
#pragma unroll
      for (int j = 0; j < 4; j++)
        b[j] = *(const short8*)&Bs[(wn * 64 + j * 16 + l16) * 64 + (((ks * 4 + quad) ^ sw)) * 8];
#pragma unroll
      for (int i = 0; i < 4; i++)
#pragma unroll
        for (int j = 0; j < 4; j++)
          acc[i][j] = __builtin_amdgcn_mfma_f32_16x16x32_bf16(a[i], b[j], acc[i][j], 0, 0, 0);
    }
    __syncthreads();
  }

#pragma unroll
  for (int i = 0; i < 4; i++) {
    const int mbase = tile_m + wm * 64 + i * 16 + quad * 4;
#pragma unroll
    for (int j = 0; j < 4; j++) {
      const int n = tile_n + wn * 64 + j * 16 + l16;
      const float bn = bo[n];
#pragma unroll
      for (int r = 0; r < 4; r++)
        out[(size_t)(mbase + r) * Dn + n] = acc[i][j][r] + bn;
    }
  }
}

extern "C" void kernel_launch(void* const* d_in, const int* in_sizes, int n_in,
                              void* d_out, int out_size, void* d_ws, size_t ws_size,
                              hipStream_t stream) {
  const float* x  = (const float*)d_in[0];
  const float* Wq = (const float*)d_in[1];
  const float* bq = (const float*)d_in[2];
  const float* Wk = (const float*)d_in[3];
  const float* bk = (const float*)d_in[4];
  const float* Wv = (const float*)d_in[5];
  const float* bv = (const float*)d_in[6];
  const float* Wo = (const float*)d_in[7];
  const float* bo = (const float*)d_in[8];
  float* out = (float*)d_out;

  // workspace carve-up (ctx aliases xb: xb dead after k_gemm_qkv) — ~75.5 MB
  char* ws = (char*)d_ws;
  u16* xb  = (u16*)ws;  ws += (size_t)Mn * Dn * 2;
  u16* WqT = (u16*)ws;  ws += (size_t)Dn * Dn * 2;
  u16* WkT = (u16*)ws;  ws += (size_t)Dn * Dn * 2;
  u16* WvT = (u16*)ws;  ws += (size_t)Dn * Dn * 2;
  u16* WoT = (u16*)ws;  ws += (size_t)Dn * Dn * 2;
  u16* qb  = (u16*)ws;  ws += (size_t)Mn * Dn * 2;
  u16* kb  = (u16*)ws;  ws += (size_t)Mn * Dn * 2;
  u16* vtb = (u16*)ws;  ws += (size_t)Mn * Dn * 2;
  u16* ctx = xb;        // alias

  k_convert_x<<<(Mn * Dn / 4) / 256, 256, 0, stream>>>((const float4*)x, (ushort4*)xb, Mn * Dn / 4);
  k_convert_w<<<1024, 256, 0, stream>>>(Wq, Wk, Wv, Wo, WqT, WkT, WvT, WoT);

  dim3 g1(Mn / 128, Dn / 128, 3);
  k_gemm_qkv<<<g1, 256, 0, stream>>>(xb, WqT, WkT, WvT, bq, bk, bv, qb, kb, vtb);

  dim3 g2(Sn / 128, Bn * Hn);
  k_attn<<<g2, 256, 0, stream>>>(qb, kb, vtb, ctx);

  dim3 g3(Mn / 128, Dn / 128);
  k_gemm_out<<<g3, 256, 0, stream>>>(ctx, WoT, bo, out);
}

// Round 6
// 287.884 us; speedup vs baseline: 1.2018x; 1.0570x over previous
//
#include <hip/hip_runtime.h>

// MHA: B=4 S=2048 D=1024 H=16 DH=64. Full bf16-MFMA pipeline (fp32 accum).

#define Bn  4
#define Sn  2048
#define Dn  1024
#define Hn  16
#define DHn 64
#define Mn  (Bn*Sn)          // 8192 rows
#define LDKV 72              // attn V LDS row stride (ushorts)

typedef unsigned short u16;
typedef __attribute__((ext_vector_type(8))) short short8;   // 8 x bf16 (4 VGPRs)
typedef __attribute__((ext_vector_type(4))) short short4v;  // 4 x bf16 (2 VGPRs)
typedef __attribute__((ext_vector_type(4))) float f32x4;    // MFMA C/D frag
typedef __attribute__((ext_vector_type(2))) unsigned int uint2v;

__device__ __forceinline__ u16 f2bf(float f) {
  unsigned u = __float_as_uint(f);
  return (u16)((u + 0x7FFFu + ((u >> 16) & 1u)) >> 16);   // RNE
}

// async 16B/lane global->LDS DMA; lds dest = wave-uniform base + lane*16
__device__ __forceinline__ void async16(const void* g, void* l) {
  __builtin_amdgcn_global_load_lds(
      (const __attribute__((address_space(1))) void*)g,
      (__attribute__((address_space(3))) void*)l, 16, 0, 0);
}

// pack 2 fp32 -> 2 bf16 (truncation) in one v_perm_b32
__device__ __forceinline__ unsigned pk2(float a, float b) {
  return __builtin_amdgcn_perm(__float_as_uint(b), __float_as_uint(a), 0x07060302u);
}

// ---------------- convert: x (f32) -> xb (bf16) ----------------
__global__ __launch_bounds__(256) void k_convert_x(
    const float4* __restrict__ x, ushort4* __restrict__ xb, int n4) {
  int i = blockIdx.x * 256 + threadIdx.x;
  if (i < n4) {
    float4 f = x[i];
    ushort4 o;
    o.x = f2bf(f.x); o.y = f2bf(f.y); o.z = f2bf(f.z); o.w = f2bf(f.w);
    xb[i] = o;
  }
}

// ---- convert+transpose weights to [N][K] bf16 via LDS 64x64 tiles ----
__global__ __launch_bounds__(256) void k_convert_w(
    const float* __restrict__ Wq, const float* __restrict__ Wk,
    const float* __restrict__ Wv, const float* __restrict__ Wo,
    u16* __restrict__ WqT, u16* __restrict__ WkT,
    u16* __restrict__ WvT, u16* __restrict__ WoT) {
  __shared__ float t[64][65];
  const int bid = blockIdx.x;          // 0..1023
  const int wsel = bid >> 8;           // 0..3
  const int idx = bid & 255;
  const int tid = threadIdx.x;
  const int c = tid & 63;
  const int r4 = tid >> 6;             // 0..3

  if (wsel < 3) {
    const float* W = (wsel == 0) ? Wq : (wsel == 1) ? Wk : Wv;
    u16* T = (wsel == 0) ? WqT : (wsel == 1) ? WkT : WvT;
    const int h = idx >> 4;
    const int d0 = (idx & 15) * 64;
    const float* src = W + (size_t)h * (Dn * DHn) + (size_t)d0 * DHn;
#pragma unroll
    for (int r = 0; r < 16; r++) {
      int row = r * 4 + r4;
      t[row][c] = src[row * DHn + c];
    }
    __syncthreads();
    u16* dst = T + (size_t)(h * 64) * Dn + d0;
#pragma unroll
    for (int r = 0; r < 16; r++) {
      int erow = r * 4 + r4;
      dst[(size_t)erow * Dn + c] = f2bf(t[c][erow]);
    }
  } else {
    const int n0 = (idx >> 4) * 64;
    const int d0 = (idx & 15) * 64;
#pragma unroll
    for (int r = 0; r < 16; r++) {
      int row = r * 4 + r4;
      t[row][c] = Wo[(size_t)(d0 + row) * Dn + n0 + c];
    }
    __syncthreads();
#pragma unroll
    for (int r = 0; r < 16; r++) {
      int nrow = r * 4 + r4;
      WoT[(size_t)(n0 + nrow) * Dn + d0 + c] = f2bf(t[c][nrow]);
    }
  }
}

// ---------------- QKV projection GEMM: 512 thr / 8 waves, 128x128 tile ----------------
// Wave tile 32x64 (acc 2x4 frags = 32 VGPR) -> 32 waves/CU resident (4 blocks).
// SWAP=1 (q,k): D computed transposed (mfma(b,a)) -> lane holds 4 contiguous e
//   -> one ushort4 store per frag, layout [B,H,S,DH].
// SWAP=0 (v): natural order -> 4 contiguous s per lane -> ushort4, [B,H,DH,S].
// q scale folds 0.125*log2(e).
template<int SWAP>
__global__ __launch_bounds__(512) void k_gemm_qkv(
    const u16* __restrict__ A, const u16* __restrict__ B0T,
    const u16* __restrict__ B1T, const float* __restrict__ bias0,
    const float* __restrict__ bias1, u16* __restrict__ out0,
    u16* __restrict__ out1) {
  const int z = blockIdx.z;
  const u16* BT = z ? B1T : B0T;
  const float* bias = z ? bias1 : bias0;
  u16* dst = z ? out1 : out0;
  const int tile_m = blockIdx.x * 128;
  const int tile_n = blockIdx.y * 128;
  const int K = Dn;

  __shared__ u16 As[128 * 64];
  __shared__ u16 Bs[128 * 64];

  const int tid = threadIdx.x;
  const int lane = tid & 63;
  const int wave = tid >> 6;                    // 0..7
  const int wm = wave & 3, wn = wave >> 2;
  const int quad = lane >> 4, l16 = lane & 15;
  const int srow8 = lane >> 3;
  const int gchunk = (lane & 7) ^ srow8;
  const int sw = l16 & 7;

  f32x4 acc[2][4];
#pragma unroll
  for (int i = 0; i < 2; i++)
#pragma unroll
    for (int j = 0; j < 4; j++) acc[i][j] = (f32x4){0.f, 0.f, 0.f, 0.f};

  for (int k0 = 0; k0 < K; k0 += 64) {
    const int rb = wave * 16;
    async16(&A[(size_t)(tile_m + rb + srow8) * K + k0 + gchunk * 8], &As[rb * 64]);
    async16(&A[(size_t)(tile_m + rb + 8 + srow8) * K + k0 + gchunk * 8], &As[(rb + 8) * 64]);
    async16(&BT[(size_t)(tile_n + rb + srow8) * K + k0 + gchunk * 8], &Bs[rb * 64]);
    async16(&BT[(size_t)(tile_n + rb + 8 + srow8) * K + k0 + gchunk * 8], &Bs[(rb + 8) * 64]);
    __syncthreads();
#pragma unroll
    for (int ks = 0; ks < 2; ++ks) {
      short8 a[2], b[4];
#pragma unroll
      for (int i = 0; i < 2; i++)
        a[i] = *(const short8*)&As[(wm * 32 + i * 16 + l16) * 64 + ((ks * 4 + quad) ^ sw) * 8];
#pragma unroll
      for (int j = 0; j < 4; j++)
        b[j] = *(const short8*)&Bs[(wn * 64 + j * 16 + l16) * 64 + ((ks * 4 + quad) ^ sw) * 8];
#pragma unroll
      for (int i = 0; i < 2; i++)
#pragma unroll
        for (int j = 0; j < 4; j++)
          acc[i][j] = SWAP
              ? __builtin_amdgcn_mfma_f32_16x16x32_bf16(b[j], a[i], acc[i][j], 0, 0, 0)
              : __builtin_amdgcn_mfma_f32_16x16x32_bf16(a[i], b[j], acc[i][j], 0, 0, 0);
    }
    __syncthreads();
  }

  if (SWAP) {
    // D^T: row = n (quad*4+r within j-block), col = s (l16)
    const float scale = (z == 0) ? 0.18033688011112042f : 1.0f;
#pragma unroll
    for (int i = 0; i < 2; i++) {
      const int s = tile_m + wm * 32 + i * 16 + l16;
      const int bb = s >> 11, sl = s & 2047;
#pragma unroll
      for (int j = 0; j < 4; j++) {
        const int nb = tile_n + wn * 64 + j * 16 + quad * 4;
        const float4 b4 = *(const float4*)&bias[nb];
        const int h = nb >> 6, e0 = nb & 63;
        ushort4 o;
        o.x = f2bf((acc[i][j][0] + b4.x) * scale);
        o.y = f2bf((acc[i][j][1] + b4.y) * scale);
        o.z = f2bf((acc[i][j][2] + b4.z) * scale);
        o.w = f2bf((acc[i][j][3] + b4.w) * scale);
        *(ushort4*)&dst[((size_t)(bb * Hn + h) * Sn + sl) * DHn + e0] = o;
      }
    }
  } else {
    // natural: row = s (quad*4+r), col = n (l16); v layout [B,H,DH,S]
#pragma unroll
    for (int i = 0; i < 2; i++) {
      const int s0 = tile_m + wm * 32 + i * 16 + quad * 4;
      const int bb = s0 >> 11, sl = s0 & 2047;
#pragma unroll
      for (int j = 0; j < 4; j++) {
        const int n = tile_n + wn * 64 + j * 16 + l16;
        const int h = n >> 6, e = n & 63;
        const float bn = bias[n];
        ushort4 o;
        o.x = f2bf(acc[i][j][0] + bn);
        o.y = f2bf(acc[i][j][1] + bn);
        o.z = f2bf(acc[i][j][2] + bn);
        o.w = f2bf(acc[i][j][3] + bn);
        *(ushort4*)&dst[((size_t)(bb * Hn + h) * DHn + e) * Sn + sl] = o;
      }
    }
  }
}

// ---------------- flash attention (unchanged from R5) ----------------
__global__ __launch_bounds__(256) void k_attn(
    const u16* __restrict__ qg, const u16* __restrict__ kg,
    const u16* __restrict__ vg, u16* __restrict__ ctx) {
  const int bh = blockIdx.y;
  const int b = bh >> 4, h = bh & 15;
  const int tid = threadIdx.x;
  const int wave = tid >> 6, lane = tid & 63;
  const int quad = lane >> 4, l16 = lane & 15;
  const int qbase = blockIdx.x * 128 + wave * 32;

  const u16* qp = qg + (size_t)bh * Sn * DHn;
  const u16* kp = kg + (size_t)bh * Sn * DHn;
  const u16* vp = vg + (size_t)bh * DHn * Sn;   // [DH][S]

  __shared__ u16 Ks[2][64 * 64];
  __shared__ u16 Vs[2][64 * LDKV];

  const int srow8 = lane >> 3;
  const int gchunk = (lane & 7) ^ srow8;
  const int sw = l16 & 7;

  const int vrow = tid >> 3;
  const int vc = tid & 7;

  short8 bq[2][2];
#pragma unroll
  for (int g2 = 0; g2 < 2; g2++) {
    bq[g2][0] = *(const short8*)&qp[(size_t)(qbase + g2 * 16 + l16) * DHn + quad * 8];
    bq[g2][1] = *(const short8*)&qp[(size_t)(qbase + g2 * 16 + l16) * DHn + 32 + quad * 8];
  }

  f32x4 octx[2][4];
#pragma unroll
  for (int g2 = 0; g2 < 2; g2++)
#pragma unroll
    for (int j = 0; j < 4; j++) octx[g2][j] = (f32x4){0.f, 0.f, 0.f, 0.f};
  float lr[2] = {0.f, 0.f};

  {
    const int rbase = wave * 16;
    async16(&kp[(size_t)(rbase + srow8) * DHn + gchunk * 8], &Ks[0][rbase * 64]);
    async16(&kp[(size_t)(rbase + 8 + srow8) * DHn + gchunk * 8], &Ks[0][(rbase + 8) * 64]);
    uint4 vv0 = *(const uint4*)&vp[(size_t)vrow * Sn + vc * 8];
    uint4 vv1 = *(const uint4*)&vp[(size_t)(32 + vrow) * Sn + vc * 8];
    *(uint4*)&Vs[0][vrow * LDKV + vc * 8] = vv0;
    *(uint4*)&Vs[0][(32 + vrow) * LDKV + vc * 8] = vv1;
  }
  __syncthreads();

  uint4 vv0, vv1;
  for (int kt = 0; kt < Sn / 64; ++kt) {
    const int cur = kt & 1, nxt = cur ^ 1;
    const bool more = (kt + 1 < Sn / 64);
    if (more) {
      const int key1 = (kt + 1) * 64;
      const int rbase = wave * 16;
      async16(&kp[(size_t)(key1 + rbase + srow8) * DHn + gchunk * 8], &Ks[nxt][rbase * 64]);
      async16(&kp[(size_t)(key1 + rbase + 8 + srow8) * DHn + gchunk * 8], &Ks[nxt][(rbase + 8) * 64]);
      vv0 = *(const uint4*)&vp[(size_t)vrow * Sn + key1 + vc * 8];
      vv1 = *(const uint4*)&vp[(size_t)(32 + vrow) * Sn + key1 + vc * 8];
    }

    short4v ap[2][4];
#pragma unroll
    for (int g = 0; g < 4; g++) {
      short8 ka0 = *(const short8*)&Ks[cur][(g * 16 + l16) * 64 + (quad ^ sw) * 8];
      short8 ka1 = *(const short8*)&Ks[cur][(g * 16 + l16) * 64 + ((quad + 4) ^ sw) * 8];
#pragma unroll
      for (int g2 = 0; g2 < 2; g2++) {
        f32x4 sc = (f32x4){0.f, 0.f, 0.f, 0.f};
        sc = __builtin_amdgcn_mfma_f32_16x16x32_bf16(ka0, bq[g2][0], sc, 0, 0, 0);
        sc = __builtin_amdgcn_mfma_f32_16x16x32_bf16(ka1, bq[g2][1], sc, 0, 0, 0);
        float p[4];
#pragma unroll
        for (int r = 0; r < 4; r++) p[r] = __builtin_amdgcn_exp2f(sc[r]);
        lr[g2] += (p[0] + p[1]) + (p[2] + p[3]);
        ap[g2][g] = __builtin_bit_cast(short4v,
            (uint2v){pk2(p[0], p[1]), pk2(p[2], p[3])});
      }
    }

#pragma unroll
    for (int j = 0; j < 4; j++) {
#pragma unroll
      for (int g = 0; g < 4; g++) {
        short4v vb = *(const short4v*)&Vs[cur][(j * 16 + l16) * LDKV + g * 16 + quad * 4];
        octx[0][j] = __builtin_amdgcn_mfma_f32_16x16x16bf16_1k(ap[0][g], vb, octx[0][j], 0, 0, 0);
        octx[1][j] = __builtin_amdgcn_mfma_f32_16x16x16bf16_1k(ap[1][g], vb, octx[1][j], 0, 0, 0);
      }
    }

    if (more) {
      *(uint4*)&Vs[nxt][vrow * LDKV + vc * 8] = vv0;
      *(uint4*)&Vs[nxt][(32 + vrow) * LDKV + vc * 8] = vv1;
    }
    __syncthreads();
  }

#pragma unroll
  for (int g2 = 0; g2 < 2; g2++) {
    lr[g2] += __shfl_xor(lr[g2], 16, 64);
    lr[g2] += __shfl_xor(lr[g2], 32, 64);
  }
  float rl[2][4];
#pragma unroll
  for (int g2 = 0; g2 < 2; g2++)
#pragma unroll
    for (int r = 0; r < 4; r++)
      rl[g2][r] = 1.0f / __shfl(lr[g2], quad * 4 + r, 64);

#pragma unroll
  for (int g2 = 0; g2 < 2; g2++)
#pragma unroll
    for (int j = 0; j < 4; j++) {
      const int n = h * DHn + j * 16 + l16;
#pragma unroll
      for (int r = 0; r < 4; r++) {
        const int s = qbase + g2 * 16 + quad * 4 + r;
        ctx[(size_t)(b * Sn + s) * Dn + n] = f2bf(octx[g2][j][r] * rl[g2][r]);
      }
    }
}

// ---------------- output projection GEMM: 512 thr / 8 waves, swapped epilogue ----------------
__global__ __launch_bounds__(512) void k_gemm_out(
    const u16* __restrict__ A, const u16* __restrict__ WoT,
    const float* __restrict__ bo, float* __restrict__ out) {
  const int tile_m = blockIdx.x * 128;
  const int tile_n = blockIdx.y * 128;
  const int K = Dn;

  __shared__ u16 As[128 * 64];
  __shared__ u16 Bs[128 * 64];

  const int tid = threadIdx.x;
  const int lane = tid & 63;
  const int wave = tid >> 6;
  const int wm = wave & 3, wn = wave >> 2;
  const int quad = lane >> 4, l16 = lane & 15;
  const int srow8 = lane >> 3;
  const int gchunk = (lane & 7) ^ srow8;
  const int sw = l16 & 7;

  f32x4 acc[2][4];
#pragma unroll
  for (int i = 0; i < 2; i++)
#pragma unroll
    for (int j = 0; j < 4; j++) acc[i][j] = (f32x4){0.f, 0.f, 0.f, 0.f};

  for (int k0 = 0; k0 < K; k0 += 64) {
    const int rb = wave * 16;
    async16(&A[(size_t)(tile_m + rb + srow8) * K + k0 + gchunk * 8], &As[rb * 64]);
    async16(&A[(size_t)(tile_m + rb + 8 + srow8) * K + k0 + gchunk * 8], &As[(rb + 8) * 64]);
    async16(&WoT[(size_t)(tile_n + rb + srow8) * K + k0 + gchunk * 8], &Bs[rb * 64]);
    async16(&WoT[(size_t)(tile_n + rb + 8 + srow8) * K + k0 + gchunk * 8], &Bs[(rb + 8) * 64]);
    __syncthreads();
#pragma unroll
    for (int ks = 0; ks < 2; ++ks) {
      short8 a[2], b[4];
#pragma unroll
      for (int i = 0; i < 2; i++)
        a[i] = *(const short8*)&As[(wm * 32 + i * 16 + l16) * 64 + ((ks * 4 + quad) ^ sw) * 8];
#pragma unroll
      for (int j = 0; j < 4; j++)
        b[j] = *(const short8*)&Bs[(wn * 64 + j * 16 + l16) * 64 + ((ks * 4 + quad) ^ sw) * 8];
#pragma unroll
      for (int i = 0; i < 2; i++)
#pragma unroll
        for (int j = 0; j < 4; j++)
          acc[i][j] = __builtin_amdgcn_mfma_f32_16x16x32_bf16(b[j], a[i], acc[i][j], 0, 0, 0);
    }
    __syncthreads();
  }

#pragma unroll
  for (int i = 0; i < 2; i++) {
    const int s = tile_m + wm * 32 + i * 16 + l16;
#pragma unroll
    for (int j = 0; j < 4; j++) {
      const int nb = tile_n + wn * 64 + j * 16 + quad * 4;
      const float4 b4 = *(const float4*)&bo[nb];
      float4 o;
      o.x = acc[i][j][0] + b4.x;
      o.y = acc[i][j][1] + b4.y;
      o.z = acc[i][j][2] + b4.z;
      o.w = acc[i][j][3] + b4.w;
      *(float4*)&out[(size_t)s * Dn + nb] = o;
    }
  }
}

extern "C" void kernel_launch(void* const* d_in, const int* in_sizes, int n_in,
                              void* d_out, int out_size, void* d_ws, size_t ws_size,
                              hipStream_t stream) {
  const float* x  = (const float*)d_in[0];
  const float* Wq = (const float*)d_in[1];
  const float* bq = (const float*)d_in[2];
  const float* Wk = (const float*)d_in[3];
  const float* bk = (const float*)d_in[4];
  const float* Wv = (const float*)d_in[5];
  const float* bv = (const float*)d_in[6];
  const float* Wo = (const float*)d_in[7];
  const float* bo = (const float*)d_in[8];
  float* out = (float*)d_out;

  // workspace carve-up (ctx aliases xb: xb dead after k_gemm_qkv) — ~75.5 MB
  char* ws = (char*)d_ws;
  u16* xb  = (u16*)ws;  ws += (size_t)Mn * Dn * 2;
  u16* WqT = (u16*)ws;  ws += (size_t)Dn * Dn * 2;
  u16* WkT = (u16*)ws;  ws += (size_t)Dn * Dn * 2;
  u16* WvT = (u16*)ws;  ws += (size_t)Dn * Dn * 2;
  u16* WoT = (u16*)ws;  ws += (size_t)Dn * Dn * 2;
  u16* qb  = (u16*)ws;  ws += (size_t)Mn * Dn * 2;
  u16* kb  = (u16*)ws;  ws += (size_t)Mn * Dn * 2;
  u16* vtb = (u16*)ws;  ws += (size_t)Mn * Dn * 2;
  u16* ctx = xb;        // alias

  k_convert_x<<<(Mn * Dn / 4) / 256, 256, 0, stream>>>((const float4*)x, (ushort4*)xb, Mn * Dn / 4);
  k_convert_w<<<1024, 256, 0, stream>>>(Wq, Wk, Wv, Wo, WqT, WkT, WvT, WoT);

  dim3 g1(Mn / 128, Dn / 128, 2);
  k_gemm_qkv<1><<<g1, 512, 0, stream>>>(xb, WqT, WkT, bq, bk, qb, kb);
  dim3 g1v(Mn / 128, Dn / 128, 1);
  k_gemm_qkv<0><<<g1v, 512, 0, stream>>>(xb, WvT, nullptr, bv, nullptr, vtb, nullptr);

  dim3 g2(Sn / 128, Bn * Hn);
  k_attn<<<g2, 256, 0, stream>>>(qb, kb, vtb, ctx);

  dim3 g3(Mn / 128, Dn / 128);
  k_gemm_out<<<g3, 512, 0, stream>>>(ctx, WoT, bo, out);
}